// Round 8
// baseline (256.111 us; speedup 1.0000x reference)
//
#include <hip/hip_runtime.h>
#include <stdint.h>
#include <stddef.h>

typedef __attribute__((ext_vector_type(4))) int i32x4;

#define AS1q __attribute__((address_space(1)))
#define AS3q __attribute__((address_space(3)))

__device__ __forceinline__ void gload16(const void* g, void* l) {
    __builtin_amdgcn_global_load_lds((const AS1q uint32_t*)g, (AS3q uint32_t*)l, 16, 0, 0);
}

#define VMCNT(n)  asm volatile("s_waitcnt vmcnt(" #n ")" ::: "memory")
#define BARRIER() asm volatile("s_barrier" ::: "memory")

#define EPSQ 1e-8f

// ---------------- Quant: one block per token (K == 4096 fast path) ----------------
__global__ __launch_bounds__(256) void quant4096(
    const float* __restrict__ x, int8_t* __restrict__ xq, float* __restrict__ sx)
{
    constexpr int K = 4096;
    const int t = blockIdx.x;
    const int tid = threadIdx.x;
    const float4* row4 = (const float4*)(x + (size_t)t * K);
    float4 v0 = row4[0 * 256 + tid];
    float4 v1 = row4[1 * 256 + tid];
    float4 v2 = row4[2 * 256 + tid];
    float4 v3 = row4[3 * 256 + tid];
    auto mx4 = [](float4 a) {
        return fmaxf(fmaxf(fabsf(a.x), fabsf(a.y)), fmaxf(fabsf(a.z), fabsf(a.w)));
    };
    float am = fmaxf(fmaxf(mx4(v0), mx4(v1)), fmaxf(mx4(v2), mx4(v3)));
    #pragma unroll
    for (int off = 32; off > 0; off >>= 1)
        am = fmaxf(am, __shfl_xor(am, off, 64));
    __shared__ float wmax[4];
    if ((tid & 63) == 0) wmax[tid >> 6] = am;
    __syncthreads();
    float r = fmaxf(fmaxf(wmax[0], wmax[1]), fmaxf(wmax[2], wmax[3]));
    const float s = fmaxf(r, EPSQ) / 127.0f;   // true fdiv: match reference
    if (tid == 0) sx[t] = s;
    int* qrow = (int*)(xq + (size_t)t * K);
    auto pack = [&](float4 a) {
        int q0 = (int)fminf(fmaxf(rintf(a.x / s), -128.f), 127.f);
        int q1 = (int)fminf(fmaxf(rintf(a.y / s), -128.f), 127.f);
        int q2 = (int)fminf(fmaxf(rintf(a.z / s), -128.f), 127.f);
        int q3 = (int)fminf(fmaxf(rintf(a.w / s), -128.f), 127.f);
        return (q0 & 255) | ((q1 & 255) << 8) | ((q2 & 255) << 16) | ((q3 & 255) << 24);
    };
    qrow[0 * 256 + tid] = pack(v0);
    qrow[1 * 256 + tid] = pack(v1);
    qrow[2 * 256 + tid] = pack(v2);
    qrow[3 * 256 + tid] = pack(v3);
}

// generic fallback (any K multiple of 4)
__global__ __launch_bounds__(256) void quant_any(
    const float* __restrict__ x, int8_t* __restrict__ xq, float* __restrict__ sx, int K)
{
    const int t = blockIdx.x;
    const int tid = threadIdx.x;
    const float* row = x + (size_t)t * K;
    float am = 0.f;
    for (int i = tid; i < K; i += 256) am = fmaxf(am, fabsf(row[i]));
    #pragma unroll
    for (int off = 32; off > 0; off >>= 1)
        am = fmaxf(am, __shfl_xor(am, off, 64));
    __shared__ float wmax[4];
    if ((tid & 63) == 0) wmax[tid >> 6] = am;
    __syncthreads();
    float r = fmaxf(fmaxf(wmax[0], wmax[1]), fmaxf(wmax[2], wmax[3]));
    const float s = fmaxf(r, EPSQ) / 127.0f;
    if (tid == 0) sx[t] = s;
    int8_t* qrow = xq + (size_t)t * K;
    for (int i = tid; i < K; i += 256) {
        float q = fminf(fmaxf(rintf(row[i] / s), -128.f), 127.f);
        qrow[i] = (int8_t)(int)q;
    }
}

// ---------------- Pack: weight arrives as int32 (harness ABI), repack to int8 ----------------
__global__ __launch_bounds__(256) void pack_w(
    const int* __restrict__ w32, int8_t* __restrict__ w8, long long n4)
{
    const long long stride = (long long)gridDim.x * 256;
    for (long long i = (long long)blockIdx.x * 256 + threadIdx.x; i < n4; i += stride) {
        int4 v = ((const int4*)w32)[i];
        ((int*)w8)[i] = (v.x & 255) | ((v.y & 255) << 8) | ((v.z & 255) << 16) | ((v.w & 255) << 24);
    }
}

// ---------------- int8 GEMM: big wave tile, B-direct-to-reg, A via LDS ----------------
// BM=256, BN=192, BK=64B. 4 waves (2x2), wave tile 128x96 = 8x6 frags of
// 16x16x64 -> 48 MFMA/wave/K-tile (979 SIMD-cyc), LDS = A only: 16KB write +
// 32KB read = 565 CU-cyc (ratio 0.58, was ~1.0 in R2..R7 - the measured limiter).
// B fragments load global->reg (B panel 768KB, L2-resident), reg-double-buffered,
// distance-1 prefetch under the MFMA window. 1 wave/SIMD (~290 VGPR, bounds(256,1)).
// Grid (M/256)*(N/192) = 16*32 = 512 = exactly 2 balanced rounds/CU.
// A LDS: R2-verified swizzle (two 64B rows per 128B phys row, x ^= (R&7)<<4,
// SQ_LDS_BANK_CONFLICT==0), linear dest via global_load_lds + inverse-swizzled
// per-lane global source (rule #21). 3 buffers, stage distance 2.
// vmcnt ledger (FIFO): per iter kt issues B(kt+1) x6 then Astage(kt+2) x4.
// Boundary kt: ops younger than Astage(kt) = B(kt)6 + As(kt+1)4 = 10, so
// VMCNT(6) guarantees Astage(kt) retired; B(kt) reg-deps are compiler-waited
// at first MFMA use. Last iter VMCNT(0). One barrier per K-tile.
__global__ __launch_bounds__(256, 1) void gemm_i8(
    const int8_t* __restrict__ xq, const int8_t* __restrict__ w,
    const float* __restrict__ sx, const float* __restrict__ scale,
    const float* __restrict__ bias, float* __restrict__ out,
    int M, int N, int K)
{
    __shared__ __align__(16) uint8_t lds[3][16384];   // A tiles only, 48KB
    const int tid  = threadIdx.x;
    const int lane = tid & 63;
    const int wv   = tid >> 6;
    const int wr   = wv >> 1, wc = wv & 1;

    // bijective XCD swizzle (m204); nwg=512 -> %8==0
    const int nwg = gridDim.x;
    const int q8 = nwg >> 3, r8 = nwg & 7;
    const int xcd = blockIdx.x & 7, idx8 = blockIdx.x >> 3;
    const int wg = (xcd < r8 ? xcd * (q8 + 1) : r8 * (q8 + 1) + (xcd - r8) * q8) + idx8;

    const int NBM = M >> 8;
    const int bm = wg % NBM;
    const int bn = wg / NBM;       // col-panel-major: B panel (768KB) L2-resident
    const int brow = bm << 8, bcol = bn * 192;

    // A staging sources (inverse-swizzled; R2-verified formula)
    const int8_t* srcA[4];
    #pragma unroll
    for (int e = 0; e < 4; ++e) {
        int li = e * 256 + tid;
        int R  = li >> 3;
        int x  = ((li & 7) << 4) ^ ((R & 7) << 4);
        srcA[e] = xq + (size_t)(brow + ((R << 1) | (x >> 6))) * K + (x & 63);
    }

    // A fragment LDS byte offsets (verified R2/R7 formula)
    int offA[8];
    #pragma unroll
    for (int m = 0; m < 8; ++m) {
        int r  = wr * 128 + m * 16 + (lane & 15);
        int R  = r >> 1;
        int x  = (((r & 1) << 6) | (lane & 48)) ^ ((R & 7) << 4);
        offA[m] = R * 128 + x;
    }

    // B fragment direct-global pointers (same logical layout as the old LDS frag)
    const int8_t* bptr[6];
    #pragma unroll
    for (int n = 0; n < 6; ++n) {
        const int col = bcol + wc * 96 + n * 16 + (lane & 15);
        bptr[n] = w + (size_t)col * K + ((lane >> 4) << 4);
    }

    i32x4 acc[8][6] = {};

    auto stageA = [&](int buf, int kt) {
        const size_t ko = (size_t)kt << 6;
        #pragma unroll
        for (int e = 0; e < 4; ++e)
            gload16(srcA[e] + ko, &lds[buf][e * 4096 + wv * 1024]);
    };

    const int NT = K >> 6;     // 64 (even)
    i32x4 bEven[6], bOdd[6];

    // prologue: A(0), A(1) staged; B(0) in flight
    stageA(0, 0);
    if (NT > 1) stageA(1, 1);
    #pragma unroll
    for (int n = 0; n < 6; ++n) bEven[n] = *(const i32x4*)(bptr[n]);

    auto body = [&](int kt, i32x4 (&bC)[6], i32x4 (&bN)[6]) {
        if (kt < NT - 1) { VMCNT(6); } else { VMCNT(0); }
        BARRIER();                                // A(kt) published; buf[(kt+2)%3] readers done
        // prefetch B(kt+1) into the other reg set
        if (kt + 1 < NT) {
            const size_t ko = (size_t)(kt + 1) << 6;
            #pragma unroll
            for (int n = 0; n < 6; ++n) bN[n] = *(const i32x4*)(bptr[n] + ko);
        }
        // stage A(kt+2)
        if (kt + 2 < NT) {
            int nb = kt + 2; nb -= (nb / 3) * 3;  // (kt+2)%3
            stageA(nb, kt + 2);
        }
        const uint8_t* buf = lds[kt % 3];
        i32x4 aF[8];
        #pragma unroll
        for (int m = 0; m < 8; ++m) aF[m] = *(const i32x4*)(buf + offA[m]);
        __builtin_amdgcn_s_setprio(1);
        #pragma unroll
        for (int m = 0; m < 8; ++m)
            #pragma unroll
            for (int n = 0; n < 6; ++n)
                acc[m][n] = __builtin_amdgcn_mfma_i32_16x16x64_i8(aF[m], bC[n], acc[m][n], 0, 0, 0);
        __builtin_amdgcn_s_setprio(0);
    };

    for (int kt = 0; kt < NT; kt += 2) {
        body(kt,     bEven, bOdd);
        body(kt + 1, bOdd,  bEven);
    }

    // epilogue: out = acc * sx[row] * scale[col] + bias[col]
    const int orow = brow + wr * 128;
    const int ocol = bcol + wc * 96;
    float sxv[8][4];
    #pragma unroll
    for (int m = 0; m < 8; ++m)
        #pragma unroll
        for (int j = 0; j < 4; ++j)
            sxv[m][j] = sx[orow + m * 16 + ((lane >> 4) << 2) + j];
    #pragma unroll
    for (int n = 0; n < 6; ++n) {
        const int col = ocol + n * 16 + (lane & 15);
        const float sc = scale[col];
        const float bi = bias[col];
        #pragma unroll
        for (int m = 0; m < 8; ++m) {
            const int rb = orow + m * 16 + ((lane >> 4) << 2);
            #pragma unroll
            for (int j = 0; j < 4; ++j)
                out[(size_t)(rb + j) * N + col] = (float)acc[m][n][j] * sxv[m][j] * sc + bi;
        }
    }
}

extern "C" void kernel_launch(void* const* d_in, const int* in_sizes, int n_in,
                              void* d_out, int out_size, void* d_ws, size_t ws_size,
                              hipStream_t stream) {
    const float* x     = (const float*)d_in[0];
    const int*   w32   = (const int*)d_in[1];     // int8 weight arrives as int32 (harness ABI)
    const float* scale = (const float*)d_in[2];
    const float* bias  = (const float*)d_in[3];
    float* out = (float*)d_out;

    const int N = in_sizes[2];           // 6144
    const int K = in_sizes[1] / N;       // 4096
    const int M = in_sizes[0] / K;       // 4096

    // ws layout: xq [M*K int8] | wq [N*K int8] | sx [M f32]
    int8_t* xqbuf = (int8_t*)d_ws;
    int8_t* wqbuf = (int8_t*)d_ws + (size_t)M * K;
    float*  sxbuf = (float*)((uint8_t*)d_ws + (size_t)M * K + (size_t)N * K);

    if (K == 4096)
        quant4096<<<M, 256, 0, stream>>>(x, xqbuf, sxbuf);
    else
        quant_any<<<M, 256, 0, stream>>>(x, xqbuf, sxbuf, K);

    pack_w<<<2048, 256, 0, stream>>>(w32, wqbuf, (long long)N * K / 4);

    const int nwg = (M / 256) * (N / 192);   // 16*32 = 512
    gemm_i8<<<nwg, 256, 0, stream>>>(xqbuf, wqbuf, sxbuf, scale, bias, out, M, N, K);
}

// Round 9
// 173.130 us; speedup vs baseline: 1.4793x; 1.4793x over previous
//
#include <hip/hip_runtime.h>
#include <stdint.h>
#include <stddef.h>

typedef __attribute__((ext_vector_type(4))) int i32x4;

#define AS1q __attribute__((address_space(1)))
#define AS3q __attribute__((address_space(3)))

__device__ __forceinline__ void gload16(const void* g, void* l) {
    __builtin_amdgcn_global_load_lds((const AS1q uint32_t*)g, (AS3q uint32_t*)l, 16, 0, 0);
}

#define BARRIER() asm volatile("s_barrier" ::: "memory")
#define LGKMW()   do { asm volatile("s_waitcnt lgkmcnt(0)" ::: "memory"); \
                       __builtin_amdgcn_sched_barrier(0); } while (0)

template<int N> __device__ __forceinline__ void vmcnt_wait() {
    if constexpr (N == 12)      asm volatile("s_waitcnt vmcnt(12)" ::: "memory");
    else if constexpr (N == 8)  asm volatile("s_waitcnt vmcnt(8)"  ::: "memory");
    else if constexpr (N == 4)  asm volatile("s_waitcnt vmcnt(4)"  ::: "memory");
    else                        asm volatile("s_waitcnt vmcnt(0)"  ::: "memory");
}
template<int V> struct IC { static constexpr int v = V; };

#define EPSQ 1e-8f

// ---------------- Quant: one block per token (K == 4096 fast path) ----------------
__global__ __launch_bounds__(256) void quant4096(
    const float* __restrict__ x, int8_t* __restrict__ xq, float* __restrict__ sx)
{
    constexpr int K = 4096;
    const int t = blockIdx.x;
    const int tid = threadIdx.x;
    const float4* row4 = (const float4*)(x + (size_t)t * K);
    float4 v0 = row4[0 * 256 + tid];
    float4 v1 = row4[1 * 256 + tid];
    float4 v2 = row4[2 * 256 + tid];
    float4 v3 = row4[3 * 256 + tid];
    auto mx4 = [](float4 a) {
        return fmaxf(fmaxf(fabsf(a.x), fabsf(a.y)), fmaxf(fabsf(a.z), fabsf(a.w)));
    };
    float am = fmaxf(fmaxf(mx4(v0), mx4(v1)), fmaxf(mx4(v2), mx4(v3)));
    #pragma unroll
    for (int off = 32; off > 0; off >>= 1)
        am = fmaxf(am, __shfl_xor(am, off, 64));
    __shared__ float wmax[4];
    if ((tid & 63) == 0) wmax[tid >> 6] = am;
    __syncthreads();
    float r = fmaxf(fmaxf(wmax[0], wmax[1]), fmaxf(wmax[2], wmax[3]));
    const float s = fmaxf(r, EPSQ) / 127.0f;   // true fdiv: match reference
    if (tid == 0) sx[t] = s;
    int* qrow = (int*)(xq + (size_t)t * K);
    auto pack = [&](float4 a) {
        int q0 = (int)fminf(fmaxf(rintf(a.x / s), -128.f), 127.f);
        int q1 = (int)fminf(fmaxf(rintf(a.y / s), -128.f), 127.f);
        int q2 = (int)fminf(fmaxf(rintf(a.z / s), -128.f), 127.f);
        int q3 = (int)fminf(fmaxf(rintf(a.w / s), -128.f), 127.f);
        return (q0 & 255) | ((q1 & 255) << 8) | ((q2 & 255) << 16) | ((q3 & 255) << 24);
    };
    qrow[0 * 256 + tid] = pack(v0);
    qrow[1 * 256 + tid] = pack(v1);
    qrow[2 * 256 + tid] = pack(v2);
    qrow[3 * 256 + tid] = pack(v3);
}

// generic fallback (any K multiple of 4)
__global__ __launch_bounds__(256) void quant_any(
    const float* __restrict__ x, int8_t* __restrict__ xq, float* __restrict__ sx, int K)
{
    const int t = blockIdx.x;
    const int tid = threadIdx.x;
    const float* row = x + (size_t)t * K;
    float am = 0.f;
    for (int i = tid; i < K; i += 256) am = fmaxf(am, fabsf(row[i]));
    #pragma unroll
    for (int off = 32; off > 0; off >>= 1)
        am = fmaxf(am, __shfl_xor(am, off, 64));
    __shared__ float wmax[4];
    if ((tid & 63) == 0) wmax[tid >> 6] = am;
    __syncthreads();
    float r = fmaxf(fmaxf(wmax[0], wmax[1]), fmaxf(wmax[2], wmax[3]));
    const float s = fmaxf(r, EPSQ) / 127.0f;
    if (tid == 0) sx[t] = s;
    int8_t* qrow = xq + (size_t)t * K;
    for (int i = tid; i < K; i += 256) {
        float q = fminf(fmaxf(rintf(row[i] / s), -128.f), 127.f);
        qrow[i] = (int8_t)(int)q;
    }
}

// ---------------- Pack: weight arrives as int32 (harness ABI), repack to int8 ----------------
__global__ __launch_bounds__(256) void pack_w(
    const int* __restrict__ w32, int8_t* __restrict__ w8, long long n4)
{
    const long long stride = (long long)gridDim.x * 256;
    for (long long i = (long long)blockIdx.x * 256 + threadIdx.x; i < n4; i += stride) {
        int4 v = ((const int4*)w32)[i];
        ((int*)w8)[i] = (v.x & 255) | ((v.y & 255) << 8) | ((v.z & 255) << 16) | ((v.w & 255) << 24);
    }
}

#define MFMAI8(a, b, c) __builtin_amdgcn_mfma_i32_16x16x64_i8(a, b, c, 0, 0, 0)
#define QUAD(MB, NB, A0, A1, A2, A3, B0, B1)                      \
    __builtin_amdgcn_s_setprio(1);                                \
    acc[MB+0][NB+0] = MFMAI8(A0, B0, acc[MB+0][NB+0]);            \
    acc[MB+1][NB+0] = MFMAI8(A1, B0, acc[MB+1][NB+0]);            \
    acc[MB+2][NB+0] = MFMAI8(A2, B0, acc[MB+2][NB+0]);            \
    acc[MB+3][NB+0] = MFMAI8(A3, B0, acc[MB+3][NB+0]);            \
    acc[MB+0][NB+1] = MFMAI8(A0, B1, acc[MB+0][NB+1]);            \
    acc[MB+1][NB+1] = MFMAI8(A1, B1, acc[MB+1][NB+1]);            \
    acc[MB+2][NB+1] = MFMAI8(A2, B1, acc[MB+2][NB+1]);            \
    acc[MB+3][NB+1] = MFMAI8(A3, B1, acc[MB+3][NB+1]);            \
    __builtin_amdgcn_s_setprio(0);

// ---------------- int8 GEMM: faithful m201 8-phase port ----------------
// BM=BN=256, 512 thr (8 waves 2M x 4N), wave tile 128x64 = 8x4 frags 16x16x64.
// Half-K-tile = 64B; iter = 2 halves (128B). LDS [2 dbuf][2 half][A 16K | B 16K]
// = 128KB -> 1 block/CU, 2 waves/SIMD (the m201 concurrency regime).
// Per half: 4 phases {ds_read subtile; barrier; lgkmcnt(0); 8-MFMA quadrant
// (setprio); barrier}. Stage issues ONLY at phase 3/7 top (after the region's
// readers drained past phase-2/6's trailing barrier -> slot-safe).
// Counted vmcnt at phase-3/7 end only: 4 loads/half-tile x 3 half-tiles in
// flight = vmcnt(12) steady; tail peeled (8,4) then (0,0). Never drains mid-loop.
// LDS swizzle: R2-counter-verified (SQ_LDS_BANK_CONFLICT==0) two-64B-rows-per-
// 128B-phys-row XOR x^=(R&7)<<4; linear gload_lds dest + inverse-swizzled
// per-lane global src (rule #21).
// Grid (M/256)*(N/256) = 16*24 = 384 (known 1.5-round placement cost ~0.75;
// two-shape split is the next lever if MfmaUtil confirms).
__global__ __launch_bounds__(512, 2) void gemm_i8(
    const int8_t* __restrict__ xq, const int8_t* __restrict__ w,
    const float* __restrict__ sx, const float* __restrict__ scale,
    const float* __restrict__ bias, float* __restrict__ out,
    int M, int N, int K)
{
    __shared__ __align__(16) uint8_t lds[2][2][32768];
    const int tid  = threadIdx.x;
    const int lane = tid & 63;
    const int wv   = tid >> 6;
    const int wr   = wv >> 2, wc = wv & 3;

    // bijective XCD swizzle (m204); nwg=384 -> %8==0
    const int nwg = gridDim.x;
    const int q8 = nwg >> 3, r8 = nwg & 7;
    const int xcd = blockIdx.x & 7, idx8 = blockIdx.x >> 3;
    const int wg = (xcd < r8 ? xcd * (q8 + 1) : r8 * (q8 + 1) + (xcd - r8) * q8) + idx8;

    const int NBM = M >> 8;
    const int bm = wg % NBM;
    const int bn = wg / NBM;       // col-panel-major: B panel (1MB) L2-resident
    const int brow = bm << 8, bcol = bn << 8;

    // staging sources (inverse-swizzled; R2-verified formula). Region = 16KB
    // (256 logical rows x 64B) packed as 128 phys rows x 128B. Chunk li covers
    // phys bytes li*16..+15; li = e*512 + tid, e in {0,1}.
    const int8_t* srcA[2];
    const int8_t* srcB[2];
    #pragma unroll
    for (int e = 0; e < 2; ++e) {
        int li = e * 512 + tid;
        int R  = li >> 3;
        int x  = ((li & 7) << 4) ^ ((R & 7) << 4);
        int r  = (R << 1) | (x >> 6);
        int c  = x & 63;
        srcA[e] = xq + (size_t)(brow + r) * K + c;
        srcB[e] = w  + (size_t)(bcol + r) * K + c;
    }

    // fragment LDS byte offsets (R2-verified formula); B region at +16KB
    int offA[8], offB[4];
    #pragma unroll
    for (int m = 0; m < 8; ++m) {
        int r  = wr * 128 + m * 16 + (lane & 15);
        int R  = r >> 1;
        int x  = (((r & 1) << 6) | (lane & 48)) ^ ((R & 7) << 4);
        offA[m] = R * 128 + x;
    }
    #pragma unroll
    for (int n = 0; n < 4; ++n) {
        int r  = wc * 64 + n * 16 + (lane & 15);
        int R  = r >> 1;
        int x  = (((r & 1) << 6) | (lane & 48)) ^ ((R & 7) << 4);
        offB[n] = 16384 + R * 128 + x;
    }

    i32x4 acc[8][4] = {};

    const int NT   = K >> 7;       // iters (128B each); 32 for K=4096
    const int hMax = NT * 2;       // half-tiles

    auto stageH = [&](int h) {     // stage half-tile h (4 gload16/thread)
        const int db = (h >> 1) & 1, hf = h & 1;
        const size_t ko = (size_t)h << 6;
        gload16(srcA[0] + ko, &lds[db][hf][wv * 1024]);
        gload16(srcA[1] + ko, &lds[db][hf][8192  + wv * 1024]);
        gload16(srcB[0] + ko, &lds[db][hf][16384 + wv * 1024]);
        gload16(srcB[1] + ko, &lds[db][hf][24576 + wv * 1024]);
    };

    // 4 phases on one half-tile buffer; stage hS at phase-3 top; wait Wc at end.
    auto half4 = [&](const uint8_t* buf, int hS, auto Wc) {
        i32x4 a0, a1, a2, a3, b0, b1, b2, b3;
        // ---- phase 0: A m0-3 + B n0-1 -> quadrant (0,0) ----
        a0 = *(const i32x4*)(buf + offA[0]);
        a1 = *(const i32x4*)(buf + offA[1]);
        a2 = *(const i32x4*)(buf + offA[2]);
        a3 = *(const i32x4*)(buf + offA[3]);
        b0 = *(const i32x4*)(buf + offB[0]);
        b1 = *(const i32x4*)(buf + offB[1]);
        BARRIER(); LGKMW();
        QUAD(0, 0, a0, a1, a2, a3, b0, b1);
        BARRIER();
        // ---- phase 1: B n2-3 -> quadrant (0,1) ----
        b2 = *(const i32x4*)(buf + offB[2]);
        b3 = *(const i32x4*)(buf + offB[3]);
        BARRIER(); LGKMW();
        QUAD(0, 2, a0, a1, a2, a3, b2, b3);
        BARRIER();
        // ---- phase 2: A m4-7 -> quadrant (1,0) ----
        a0 = *(const i32x4*)(buf + offA[4]);
        a1 = *(const i32x4*)(buf + offA[5]);
        a2 = *(const i32x4*)(buf + offA[6]);
        a3 = *(const i32x4*)(buf + offA[7]);
        BARRIER(); LGKMW();
        QUAD(4, 0, a0, a1, a2, a3, b0, b1);
        BARRIER();
        // ---- phase 3: stage + quadrant (1,1) + counted wait ----
        if (hS < hMax) stageH(hS);
        QUAD(4, 2, a0, a1, a2, a3, b2, b3);
        vmcnt_wait<decltype(Wc)::v>();
        BARRIER();
    };

    // prologue: 4 half-tiles staged (16 loads out); wait h0, keep 12 in flight
    stageH(0); stageH(1); stageH(2); stageH(3);
    vmcnt_wait<12>(); BARRIER();

    for (int it = 0; it < NT - 2; ++it) {
        const int db = it & 1;
        half4(&lds[db][0][0], 2 * it + 4, IC<12>{});
        half4(&lds[db][1][0], 2 * it + 5, IC<12>{});
    }
    {   // it = NT-2: no more stages; retire h_{2NT-3}, h_{2NT-2}
        const int db = (NT - 2) & 1;
        half4(&lds[db][0][0], hMax, IC<8>{});
        half4(&lds[db][1][0], hMax, IC<4>{});
    }
    {   // it = NT-1: drain
        const int db = (NT - 1) & 1;
        half4(&lds[db][0][0], hMax, IC<0>{});
        half4(&lds[db][1][0], hMax, IC<0>{});
    }

    // epilogue: out = acc * sx[row] * scale[col] + bias[col]
    const int orow = brow + wr * 128;
    const int ocol = bcol + wc * 64;
    float sxv[8][4];
    #pragma unroll
    for (int m = 0; m < 8; ++m)
        #pragma unroll
        for (int j = 0; j < 4; ++j)
            sxv[m][j] = sx[orow + m * 16 + ((lane >> 4) << 2) + j];
    #pragma unroll
    for (int n = 0; n < 4; ++n) {
        const int col = ocol + n * 16 + (lane & 15);
        const float sc = scale[col];
        const float bi = bias[col];
        #pragma unroll
        for (int m = 0; m < 8; ++m) {
            const int rb = orow + m * 16 + ((lane >> 4) << 2);
            #pragma unroll
            for (int j = 0; j < 4; ++j)
                out[(size_t)(rb + j) * N + col] = (float)acc[m][n][j] * sxv[m][j] * sc + bi;
        }
    }
}

extern "C" void kernel_launch(void* const* d_in, const int* in_sizes, int n_in,
                              void* d_out, int out_size, void* d_ws, size_t ws_size,
                              hipStream_t stream) {
    const float* x     = (const float*)d_in[0];
    const int*   w32   = (const int*)d_in[1];     // int8 weight arrives as int32 (harness ABI)
    const float* scale = (const float*)d_in[2];
    const float* bias  = (const float*)d_in[3];
    float* out = (float*)d_out;

    const int N = in_sizes[2];           // 6144
    const int K = in_sizes[1] / N;       // 4096
    const int M = in_sizes[0] / K;       // 4096

    // ws layout: xq [M*K int8] | wq [N*K int8] | sx [M f32]
    int8_t* xqbuf = (int8_t*)d_ws;
    int8_t* wqbuf = (int8_t*)d_ws + (size_t)M * K;
    float*  sxbuf = (float*)((uint8_t*)d_ws + (size_t)M * K + (size_t)N * K);

    if (K == 4096)
        quant4096<<<M, 256, 0, stream>>>(x, xqbuf, sxbuf);
    else
        quant_any<<<M, 256, 0, stream>>>(x, xqbuf, sxbuf, K);

    pack_w<<<2048, 256, 0, stream>>>(w32, wqbuf, (long long)N * K / 4);

    const int nwg = (M / 256) * (N / 256);   // 16*24 = 384
    gemm_i8<<<nwg, 512, 0, stream>>>(xqbuf, wqbuf, sxbuf, scale, bias, out, M, N, K);
}

// Round 10
// 169.370 us; speedup vs baseline: 1.5121x; 1.0222x over previous
//
#include <hip/hip_runtime.h>
#include <stdint.h>
#include <stddef.h>

typedef __attribute__((ext_vector_type(4))) int i32x4;

#define AS1q __attribute__((address_space(1)))
#define AS3q __attribute__((address_space(3)))

__device__ __forceinline__ void gload16(const void* g, void* l) {
    __builtin_amdgcn_global_load_lds((const AS1q uint32_t*)g, (AS3q uint32_t*)l, 16, 0, 0);
}

#define VMCNT(n)  asm volatile("s_waitcnt vmcnt(" #n ")" ::: "memory")
#define BARRIER() asm volatile("s_barrier" ::: "memory")

#define EPSQ 1e-8f

// ---------------- Quant: one block per token (K == 4096 fast path) ----------------
__global__ __launch_bounds__(256) void quant4096(
    const float* __restrict__ x, int8_t* __restrict__ xq, float* __restrict__ sx)
{
    constexpr int K = 4096;
    const int t = blockIdx.x;
    const int tid = threadIdx.x;
    const float4* row4 = (const float4*)(x + (size_t)t * K);
    float4 v0 = row4[0 * 256 + tid];
    float4 v1 = row4[1 * 256 + tid];
    float4 v2 = row4[2 * 256 + tid];
    float4 v3 = row4[3 * 256 + tid];
    auto mx4 = [](float4 a) {
        return fmaxf(fmaxf(fabsf(a.x), fabsf(a.y)), fmaxf(fabsf(a.z), fabsf(a.w)));
    };
    float am = fmaxf(fmaxf(mx4(v0), mx4(v1)), fmaxf(mx4(v2), mx4(v3)));
    #pragma unroll
    for (int off = 32; off > 0; off >>= 1)
        am = fmaxf(am, __shfl_xor(am, off, 64));
    __shared__ float wmax[4];
    if ((tid & 63) == 0) wmax[tid >> 6] = am;
    __syncthreads();
    float r = fmaxf(fmaxf(wmax[0], wmax[1]), fmaxf(wmax[2], wmax[3]));
    const float s = fmaxf(r, EPSQ) / 127.0f;   // true fdiv: match reference
    if (tid == 0) sx[t] = s;
    int* qrow = (int*)(xq + (size_t)t * K);
    auto pack = [&](float4 a) {
        int q0 = (int)fminf(fmaxf(rintf(a.x / s), -128.f), 127.f);
        int q1 = (int)fminf(fmaxf(rintf(a.y / s), -128.f), 127.f);
        int q2 = (int)fminf(fmaxf(rintf(a.z / s), -128.f), 127.f);
        int q3 = (int)fminf(fmaxf(rintf(a.w / s), -128.f), 127.f);
        return (q0 & 255) | ((q1 & 255) << 8) | ((q2 & 255) << 16) | ((q3 & 255) << 24);
    };
    qrow[0 * 256 + tid] = pack(v0);
    qrow[1 * 256 + tid] = pack(v1);
    qrow[2 * 256 + tid] = pack(v2);
    qrow[3 * 256 + tid] = pack(v3);
}

// generic fallback (any K multiple of 4)
__global__ __launch_bounds__(256) void quant_any(
    const float* __restrict__ x, int8_t* __restrict__ xq, float* __restrict__ sx, int K)
{
    const int t = blockIdx.x;
    const int tid = threadIdx.x;
    const float* row = x + (size_t)t * K;
    float am = 0.f;
    for (int i = tid; i < K; i += 256) am = fmaxf(am, fabsf(row[i]));
    #pragma unroll
    for (int off = 32; off > 0; off >>= 1)
        am = fmaxf(am, __shfl_xor(am, off, 64));
    __shared__ float wmax[4];
    if ((tid & 63) == 0) wmax[tid >> 6] = am;
    __syncthreads();
    float r = fmaxf(fmaxf(wmax[0], wmax[1]), fmaxf(wmax[2], wmax[3]));
    const float s = fmaxf(r, EPSQ) / 127.0f;
    if (tid == 0) sx[t] = s;
    int8_t* qrow = xq + (size_t)t * K;
    for (int i = tid; i < K; i += 256) {
        float q = fminf(fmaxf(rintf(row[i] / s), -128.f), 127.f);
        qrow[i] = (int8_t)(int)q;
    }
}

// ---------------- Pack: weight arrives as int32 (harness ABI), repack to int8 ----------------
__global__ __launch_bounds__(256) void pack_w(
    const int* __restrict__ w32, int8_t* __restrict__ w8, long long n4)
{
    const long long stride = (long long)gridDim.x * 256;
    for (long long i = (long long)blockIdx.x * 256 + threadIdx.x; i < n4; i += stride) {
        int4 v = ((const int4*)w32)[i];
        ((int*)w8)[i] = (v.x & 255) | ((v.y & 255) << 8) | ((v.z & 255) << 16) | ((v.w & 255) << 24);
    }
}

#define MFMAI8(a, b, c) __builtin_amdgcn_mfma_i32_16x16x64_i8(a, b, c, 0, 0, 0)

// ---------------- int8 GEMM: reg-frag double-buffer, 1 barrier/half-tile ----------------
// BM=128, BN=192. 4 waves (1x4), wave tile 128x48 = 8x3 frags 16x16x64.
// Half-tile = 64B K. Per half per wave: 24 MFMA (490 SIMD-cyc) + 11 ds_read_b128.
// KEY CHANGE vs R2..R9: ds_reads for half h+1 are issued DURING half h's MFMA
// cluster (independent register sets, statically double-buffered per rule #20)
// -> LDS pipe overlaps matrix pipe within each wave; no lgkm asm (compiler
// emits precise waits; read->use slack = one full MFMA cluster).
// One barrier + one counted VMCNT per half (not per phase).
// LDS: 4 buffers x (A 8KB | B 12KB) = 80KB -> EXACTLY 2 blocks/CU (cross-block
// stagger, m114). Grid (M/128)*(N/192) = 32*32 = 1024 = 4.0 blocks/CU (zero
// placement waste). VGPR: acc 96 AGPR + 2x44 frag + addr ~ 220 total, 2 w/SIMD.
// Swizzle: R2-counter-verified (SQ_LDS_BANK_CONFLICT==0) two-64B-logical-rows-
// per-128B-phys-row, x ^= (R&7)<<4; linear gload_lds dest + inverse-swizzled
// per-lane global src (rule #21).
// Ledger (5 gloads/thread/half, distance 3): prologue stages h0,h1,h2 (15 out),
// VMCNT(5) retires h0,h1. Top of half h (h>=1): outstanding = stage(h+1),(h+2)
// = 10 -> VMCNT(5) retires stage(h+1) (needed: frags(h+1) prefetched THIS half);
// barrier makes it cross-wave. h=NH-2: VMCNT(0) retires last stage. Buffer
// write safety: stage(h+3) overwrites buf[(h-1)&3], whose last reads (frags h-1,
// body h-2) are fenced by the h-1 and h top barriers.
__global__ __launch_bounds__(256, 2) void gemm_i8(
    const int8_t* __restrict__ xq, const int8_t* __restrict__ w,
    const float* __restrict__ sx, const float* __restrict__ scale,
    const float* __restrict__ bias, float* __restrict__ out,
    int M, int N, int K)
{
    __shared__ __align__(16) uint8_t lds[4][20480];   // [buf][A 8KB | B 12KB]
    const int tid  = threadIdx.x;
    const int lane = tid & 63;
    const int wv   = tid >> 6;
    const int wc   = wv;                 // 1M x 4N wave grid

    // bijective XCD swizzle (m204); nwg=1024 -> %8==0
    const int nwg = gridDim.x;
    const int q8 = nwg >> 3, r8 = nwg & 7;
    const int xcd = blockIdx.x & 7, idx8 = blockIdx.x >> 3;
    const int wg = (xcd < r8 ? xcd * (q8 + 1) : r8 * (q8 + 1) + (xcd - r8) * q8) + idx8;

    const int NBM = M >> 7;
    const int bm = wg % NBM;
    const int bn = wg / NBM;             // col-panel-major: B panel (768KB) L2-resident
    const int brow = bm << 7, bcol = bn * 192;

    // staging sources (inverse-swizzled; R2-verified formula)
    const int8_t* srcA[2];
    const int8_t* srcB[3];
    #pragma unroll
    for (int e = 0; e < 2; ++e) {
        int li = e * 256 + tid;
        int R  = li >> 3;
        int x  = ((li & 7) << 4) ^ ((R & 7) << 4);
        srcA[e] = xq + (size_t)(brow + ((R << 1) | (x >> 6))) * K + (x & 63);
    }
    #pragma unroll
    for (int e = 0; e < 3; ++e) {
        int li = e * 256 + tid;
        int R  = li >> 3;
        int x  = ((li & 7) << 4) ^ ((R & 7) << 4);
        srcB[e] = w + (size_t)(bcol + ((R << 1) | (x >> 6))) * K + (x & 63);
    }

    // fragment LDS byte offsets (R2-verified formula); B region at +8KB
    int offA[8], offB[3];
    #pragma unroll
    for (int m = 0; m < 8; ++m) {
        int r  = m * 16 + (lane & 15);
        int R  = r >> 1;
        int x  = (((r & 1) << 6) | (lane & 48)) ^ ((R & 7) << 4);
        offA[m] = R * 128 + x;
    }
    #pragma unroll
    for (int n = 0; n < 3; ++n) {
        int r  = wc * 48 + n * 16 + (lane & 15);
        int R  = r >> 1;
        int x  = (((r & 1) << 6) | (lane & 48)) ^ ((R & 7) << 4);
        offB[n] = 8192 + R * 128 + x;
    }

    i32x4 acc[8][3] = {};

    auto stage = [&](int h) {            // 5 gloads/thread into buf[h&3]
        const int b = h & 3;
        const size_t ko = (size_t)h << 6;
        gload16(srcA[0] + ko, &lds[b][wv * 1024]);
        gload16(srcA[1] + ko, &lds[b][4096 + wv * 1024]);
        gload16(srcB[0] + ko, &lds[b][8192  + wv * 1024]);
        gload16(srcB[1] + ko, &lds[b][12288 + wv * 1024]);
        gload16(srcB[2] + ko, &lds[b][16384 + wv * 1024]);
    };
    auto readf = [&](int h, i32x4 (&fa)[8], i32x4 (&fb)[3]) {
        const uint8_t* buf = lds[h & 3];
        #pragma unroll
        for (int m = 0; m < 8; ++m) fa[m] = *(const i32x4*)(buf + offA[m]);
        #pragma unroll
        for (int n = 0; n < 3; ++n) fb[n] = *(const i32x4*)(buf + offB[n]);
    };
    auto mfma24 = [&](i32x4 (&fa)[8], i32x4 (&fb)[3]) {
        __builtin_amdgcn_s_setprio(1);
        #pragma unroll
        for (int m = 0; m < 8; ++m)
            #pragma unroll
            for (int n = 0; n < 3; ++n)
                acc[m][n] = MFMAI8(fa[m], fb[n], acc[m][n]);
        __builtin_amdgcn_s_setprio(0);
    };

    const int NH = K >> 6;               // 64 half-tiles
    i32x4 fa0[8], fb0[3], fa1[8], fb1[3];

    stage(0); stage(1); stage(2);        // 15 out
    VMCNT(5); BARRIER();                 // h0,h1 retired; h2 in flight
    readf(0, fa0, fb0);

    for (int h = 0; h < NH; h += 2) {
        // ---- even half: compute (fa0,fb0), prefetch h+1 -> (fa1,fb1) ----
        if (h > 0) {
            if (h < NH - 2) { VMCNT(5); } else { VMCNT(0); }
            BARRIER();
        }
        if (h + 3 < NH) stage(h + 3);
        if (h + 1 < NH) readf(h + 1, fa1, fb1);
        mfma24(fa0, fb0);
        // ---- odd half g=h+1: compute (fa1,fb1), prefetch g+1 -> (fa0,fb0) ----
        {
            const int g = h + 1;
            if (g < NH - 2) { VMCNT(5); } else { VMCNT(0); }
            BARRIER();
            if (g + 3 < NH) stage(g + 3);
            if (g + 1 < NH) readf(g + 1, fa0, fb0);
            mfma24(fa1, fb1);
        }
    }

    // epilogue: out = acc * sx[row] * scale[col] + bias[col]
    const int ocol = bcol + wc * 48;
    float sxv[8][4];
    #pragma unroll
    for (int m = 0; m < 8; ++m)
        #pragma unroll
        for (int j = 0; j < 4; ++j)
            sxv[m][j] = sx[brow + m * 16 + ((lane >> 4) << 2) + j];
    #pragma unroll
    for (int n = 0; n < 3; ++n) {
        const int col = ocol + n * 16 + (lane & 15);
        const float sc = scale[col];
        const float bi = bias[col];
        #pragma unroll
        for (int m = 0; m < 8; ++m) {
            const int rb = brow + m * 16 + ((lane >> 4) << 2);
            #pragma unroll
            for (int j = 0; j < 4; ++j)
                out[(size_t)(rb + j) * N + col] = (float)acc[m][n][j] * sxv[m][j] * sc + bi;
        }
    }
}

extern "C" void kernel_launch(void* const* d_in, const int* in_sizes, int n_in,
                              void* d_out, int out_size, void* d_ws, size_t ws_size,
                              hipStream_t stream) {
    const float* x     = (const float*)d_in[0];
    const int*   w32   = (const int*)d_in[1];     // int8 weight arrives as int32 (harness ABI)
    const float* scale = (const float*)d_in[2];
    const float* bias  = (const float*)d_in[3];
    float* out = (float*)d_out;

    const int N = in_sizes[2];           // 6144
    const int K = in_sizes[1] / N;       // 4096
    const int M = in_sizes[0] / K;       // 4096

    // ws layout: xq [M*K int8] | wq [N*K int8] | sx [M f32]
    int8_t* xqbuf = (int8_t*)d_ws;
    int8_t* wqbuf = (int8_t*)d_ws + (size_t)M * K;
    float*  sxbuf = (float*)((uint8_t*)d_ws + (size_t)M * K + (size_t)N * K);

    if (K == 4096)
        quant4096<<<M, 256, 0, stream>>>(x, xqbuf, sxbuf);
    else
        quant_any<<<M, 256, 0, stream>>>(x, xqbuf, sxbuf, K);

    pack_w<<<2048, 256, 0, stream>>>(w32, wqbuf, (long long)N * K / 4);

    const int nwg = (M / 128) * (N / 192);   // 32*32 = 1024
    gemm_i8<<<nwg, 256, 0, stream>>>(xqbuf, wqbuf, sxbuf, scale, bias, out, M, N, K);
}

// Round 11
// 169.169 us; speedup vs baseline: 1.5139x; 1.0012x over previous
//
#include <hip/hip_runtime.h>
#include <stdint.h>
#include <stddef.h>

typedef __attribute__((ext_vector_type(4))) int i32x4;

#define AS1q __attribute__((address_space(1)))
#define AS3q __attribute__((address_space(3)))

__device__ __forceinline__ void gload16(const void* g, void* l) {
    __builtin_amdgcn_global_load_lds((const AS1q uint32_t*)g, (AS3q uint32_t*)l, 16, 0, 0);
}

#define VMCNT(n)  asm volatile("s_waitcnt vmcnt(" #n ")" ::: "memory")
#define BARRIER() asm volatile("s_barrier" ::: "memory")
#define SCHEDPIN() __builtin_amdgcn_sched_barrier(0)

#define EPSQ 1e-8f

// ---------------- Quant: one block per token (K == 4096 fast path) ----------------
__global__ __launch_bounds__(256) void quant4096(
    const float* __restrict__ x, int8_t* __restrict__ xq, float* __restrict__ sx)
{
    constexpr int K = 4096;
    const int t = blockIdx.x;
    const int tid = threadIdx.x;
    const float4* row4 = (const float4*)(x + (size_t)t * K);
    float4 v0 = row4[0 * 256 + tid];
    float4 v1 = row4[1 * 256 + tid];
    float4 v2 = row4[2 * 256 + tid];
    float4 v3 = row4[3 * 256 + tid];
    auto mx4 = [](float4 a) {
        return fmaxf(fmaxf(fabsf(a.x), fabsf(a.y)), fmaxf(fabsf(a.z), fabsf(a.w)));
    };
    float am = fmaxf(fmaxf(mx4(v0), mx4(v1)), fmaxf(mx4(v2), mx4(v3)));
    #pragma unroll
    for (int off = 32; off > 0; off >>= 1)
        am = fmaxf(am, __shfl_xor(am, off, 64));
    __shared__ float wmax[4];
    if ((tid & 63) == 0) wmax[tid >> 6] = am;
    __syncthreads();
    float r = fmaxf(fmaxf(wmax[0], wmax[1]), fmaxf(wmax[2], wmax[3]));
    const float s = fmaxf(r, EPSQ) / 127.0f;   // true fdiv: match reference
    if (tid == 0) sx[t] = s;
    int* qrow = (int*)(xq + (size_t)t * K);
    auto pack = [&](float4 a) {
        int q0 = (int)fminf(fmaxf(rintf(a.x / s), -128.f), 127.f);
        int q1 = (int)fminf(fmaxf(rintf(a.y / s), -128.f), 127.f);
        int q2 = (int)fminf(fmaxf(rintf(a.z / s), -128.f), 127.f);
        int q3 = (int)fminf(fmaxf(rintf(a.w / s), -128.f), 127.f);
        return (q0 & 255) | ((q1 & 255) << 8) | ((q2 & 255) << 16) | ((q3 & 255) << 24);
    };
    qrow[0 * 256 + tid] = pack(v0);
    qrow[1 * 256 + tid] = pack(v1);
    qrow[2 * 256 + tid] = pack(v2);
    qrow[3 * 256 + tid] = pack(v3);
}

// generic fallback (any K multiple of 4)
__global__ __launch_bounds__(256) void quant_any(
    const float* __restrict__ x, int8_t* __restrict__ xq, float* __restrict__ sx, int K)
{
    const int t = blockIdx.x;
    const int tid = threadIdx.x;
    const float* row = x + (size_t)t * K;
    float am = 0.f;
    for (int i = tid; i < K; i += 256) am = fmaxf(am, fabsf(row[i]));
    #pragma unroll
    for (int off = 32; off > 0; off >>= 1)
        am = fmaxf(am, __shfl_xor(am, off, 64));
    __shared__ float wmax[4];
    if ((tid & 63) == 0) wmax[tid >> 6] = am;
    __syncthreads();
    float r = fmaxf(fmaxf(wmax[0], wmax[1]), fmaxf(wmax[2], wmax[3]));
    const float s = fmaxf(r, EPSQ) / 127.0f;
    if (tid == 0) sx[t] = s;
    int8_t* qrow = xq + (size_t)t * K;
    for (int i = tid; i < K; i += 256) {
        float q = fminf(fmaxf(rintf(row[i] / s), -128.f), 127.f);
        qrow[i] = (int8_t)(int)q;
    }
}

// ---------------- Pack: weight arrives as int32 (harness ABI), repack to int8 ----------------
__global__ __launch_bounds__(256) void pack_w(
    const int* __restrict__ w32, int8_t* __restrict__ w8, long long n4)
{
    const long long stride = (long long)gridDim.x * 256;
    for (long long i = (long long)blockIdx.x * 256 + threadIdx.x; i < n4; i += stride) {
        int4 v = ((const int4*)w32)[i];
        ((int*)w8)[i] = (v.x & 255) | ((v.y & 255) << 8) | ((v.z & 255) << 16) | ((v.w & 255) << 24);
    }
}

#define MFMAI8(a, b, c) __builtin_amdgcn_mfma_i32_16x16x64_i8(a, b, c, 0, 0, 0)

// ---------------- int8 GEMM: reg-frag double-buffer + SCHED-PINNED overlap ----------------
// Identical geometry/ledger to R10 (BM=128, BN=192, 4 waves 1x4, wave tile
// 128x48, 4 LDS buffers x 20KB = 80KB, 2 blocks/CU, grid 1024 = 4.0/CU,
// R2-counter-verified swizzle, VMCNT(5)/barrier per half-tile).
// NEW: __builtin_amdgcn_sched_barrier(0) between readf(h+1) and mfma24(h).
// R10's VGPR_Count=112 proved the compiler sank the prefetch ds_reads to just
// before their MFMA use (two live frag sets need ~130+ VGPRs), re-serializing
// read->MFMA. The pin forces: ds_reads(h+1) ISSUED, then MFMA cluster(h) runs
// while the LDS pipe drains -> intra-wave LDS/MFMA overlap, x2 waves/SIMD.
__global__ __launch_bounds__(256, 2) void gemm_i8(
    const int8_t* __restrict__ xq, const int8_t* __restrict__ w,
    const float* __restrict__ sx, const float* __restrict__ scale,
    const float* __restrict__ bias, float* __restrict__ out,
    int M, int N, int K)
{
    __shared__ __align__(16) uint8_t lds[4][20480];   // [buf][A 8KB | B 12KB]
    const int tid  = threadIdx.x;
    const int lane = tid & 63;
    const int wv   = tid >> 6;
    const int wc   = wv;                 // 1M x 4N wave grid

    // bijective XCD swizzle (m204); nwg=1024 -> %8==0
    const int nwg = gridDim.x;
    const int q8 = nwg >> 3, r8 = nwg & 7;
    const int xcd = blockIdx.x & 7, idx8 = blockIdx.x >> 3;
    const int wg = (xcd < r8 ? xcd * (q8 + 1) : r8 * (q8 + 1) + (xcd - r8) * q8) + idx8;

    const int NBM = M >> 7;
    const int bm = wg % NBM;
    const int bn = wg / NBM;             // col-panel-major: B panel (768KB) L2-resident
    const int brow = bm << 7, bcol = bn * 192;

    // staging sources (inverse-swizzled; R2-verified formula)
    const int8_t* srcA[2];
    const int8_t* srcB[3];
    #pragma unroll
    for (int e = 0; e < 2; ++e) {
        int li = e * 256 + tid;
        int R  = li >> 3;
        int x  = ((li & 7) << 4) ^ ((R & 7) << 4);
        srcA[e] = xq + (size_t)(brow + ((R << 1) | (x >> 6))) * K + (x & 63);
    }
    #pragma unroll
    for (int e = 0; e < 3; ++e) {
        int li = e * 256 + tid;
        int R  = li >> 3;
        int x  = ((li & 7) << 4) ^ ((R & 7) << 4);
        srcB[e] = w + (size_t)(bcol + ((R << 1) | (x >> 6))) * K + (x & 63);
    }

    // fragment LDS byte offsets (R2-verified formula); B region at +8KB
    int offA[8], offB[3];
    #pragma unroll
    for (int m = 0; m < 8; ++m) {
        int r  = m * 16 + (lane & 15);
        int R  = r >> 1;
        int x  = (((r & 1) << 6) | (lane & 48)) ^ ((R & 7) << 4);
        offA[m] = R * 128 + x;
    }
    #pragma unroll
    for (int n = 0; n < 3; ++n) {
        int r  = wc * 48 + n * 16 + (lane & 15);
        int R  = r >> 1;
        int x  = (((r & 1) << 6) | (lane & 48)) ^ ((R & 7) << 4);
        offB[n] = 8192 + R * 128 + x;
    }

    i32x4 acc[8][3] = {};

    auto stage = [&](int h) {            // 5 gloads/thread into buf[h&3]
        const int b = h & 3;
        const size_t ko = (size_t)h << 6;
        gload16(srcA[0] + ko, &lds[b][wv * 1024]);
        gload16(srcA[1] + ko, &lds[b][4096 + wv * 1024]);
        gload16(srcB[0] + ko, &lds[b][8192  + wv * 1024]);
        gload16(srcB[1] + ko, &lds[b][12288 + wv * 1024]);
        gload16(srcB[2] + ko, &lds[b][16384 + wv * 1024]);
    };
    auto readf = [&](int h, i32x4 (&fa)[8], i32x4 (&fb)[3]) {
        const uint8_t* buf = lds[h & 3];
        #pragma unroll
        for (int m = 0; m < 8; ++m) fa[m] = *(const i32x4*)(buf + offA[m]);
        #pragma unroll
        for (int n = 0; n < 3; ++n) fb[n] = *(const i32x4*)(buf + offB[n]);
    };
    auto mfma24 = [&](i32x4 (&fa)[8], i32x4 (&fb)[3]) {
        __builtin_amdgcn_s_setprio(1);
        #pragma unroll
        for (int m = 0; m < 8; ++m)
            #pragma unroll
            for (int n = 0; n < 3; ++n)
                acc[m][n] = MFMAI8(fa[m], fb[n], acc[m][n]);
        __builtin_amdgcn_s_setprio(0);
    };

    const int NH = K >> 6;               // 64 half-tiles
    i32x4 fa0[8], fb0[3], fa1[8], fb1[3];

    stage(0); stage(1); stage(2);        // 15 out
    VMCNT(5); BARRIER();                 // h0,h1 retired; h2 in flight
    readf(0, fa0, fb0);

    for (int h = 0; h < NH; h += 2) {
        // ---- even half: compute (fa0,fb0), prefetch h+1 -> (fa1,fb1) ----
        if (h > 0) {
            if (h < NH - 2) { VMCNT(5); } else { VMCNT(0); }
            BARRIER();
        }
        if (h + 3 < NH) stage(h + 3);
        if (h + 1 < NH) readf(h + 1, fa1, fb1);
        SCHEDPIN();                      // reads ISSUED before the MFMA cluster
        mfma24(fa0, fb0);
        // ---- odd half g=h+1: compute (fa1,fb1), prefetch g+1 -> (fa0,fb0) ----
        {
            const int g = h + 1;
            if (g < NH - 2) { VMCNT(5); } else { VMCNT(0); }
            BARRIER();
            if (g + 3 < NH) stage(g + 3);
            if (g + 1 < NH) readf(g + 1, fa0, fb0);
            SCHEDPIN();
            mfma24(fa1, fb1);
        }
    }

    // epilogue: out = acc * sx[row] * scale[col] + bias[col]
    const int ocol = bcol + wc * 48;
    float sxv[8][4];
    #pragma unroll
    for (int m = 0; m < 8; ++m)
        #pragma unroll
        for (int j = 0; j < 4; ++j)
            sxv[m][j] = sx[brow + m * 16 + ((lane >> 4) << 2) + j];
    #pragma unroll
    for (int n = 0; n < 3; ++n) {
        const int col = ocol + n * 16 + (lane & 15);
        const float sc = scale[col];
        const float bi = bias[col];
        #pragma unroll
        for (int m = 0; m < 8; ++m) {
            const int rb = brow + m * 16 + ((lane >> 4) << 2);
            #pragma unroll
            for (int j = 0; j < 4; ++j)
                out[(size_t)(rb + j) * N + col] = (float)acc[m][n][j] * sxv[m][j] * sc + bi;
        }
    }
}

extern "C" void kernel_launch(void* const* d_in, const int* in_sizes, int n_in,
                              void* d_out, int out_size, void* d_ws, size_t ws_size,
                              hipStream_t stream) {
    const float* x     = (const float*)d_in[0];
    const int*   w32   = (const int*)d_in[1];     // int8 weight arrives as int32 (harness ABI)
    const float* scale = (const float*)d_in[2];
    const float* bias  = (const float*)d_in[3];
    float* out = (float*)d_out;

    const int N = in_sizes[2];           // 6144
    const int K = in_sizes[1] / N;       // 4096
    const int M = in_sizes[0] / K;       // 4096

    // ws layout: xq [M*K int8] | wq [N*K int8] | sx [M f32]
    int8_t* xqbuf = (int8_t*)d_ws;
    int8_t* wqbuf = (int8_t*)d_ws + (size_t)M * K;
    float*  sxbuf = (float*)((uint8_t*)d_ws + (size_t)M * K + (size_t)N * K);

    if (K == 4096)
        quant4096<<<M, 256, 0, stream>>>(x, xqbuf, sxbuf);
    else
        quant_any<<<M, 256, 0, stream>>>(x, xqbuf, sxbuf, K);

    pack_w<<<2048, 256, 0, stream>>>(w32, wqbuf, (long long)N * K / 4);

    const int nwg = (M / 128) * (N / 192);   // 32*32 = 1024
    gemm_i8<<<nwg, 256, 0, stream>>>(xqbuf, wqbuf, sxbuf, scale, bias, out, M, N, K);
}

// Round 12
// 142.158 us; speedup vs baseline: 1.8016x; 1.1900x over previous
//
#include <hip/hip_runtime.h>
#include <stdint.h>
#include <stddef.h>

typedef __attribute__((ext_vector_type(4))) int i32x4;

#define AS1q __attribute__((address_space(1)))
#define AS3q __attribute__((address_space(3)))

__device__ __forceinline__ void gload16(const void* g, void* l) {
    __builtin_amdgcn_global_load_lds((const AS1q uint32_t*)g, (AS3q uint32_t*)l, 16, 0, 0);
}

#define VMCNT0()  asm volatile("s_waitcnt vmcnt(0)" ::: "memory")
#define BARRIER() asm volatile("s_barrier" ::: "memory")
#define SB()      __builtin_amdgcn_sched_barrier(0)
#define SP1()     __builtin_amdgcn_s_setprio(1)
#define SP0()     __builtin_amdgcn_s_setprio(0)
#define MFMAI8(a, b, c) __builtin_amdgcn_mfma_i32_16x16x64_i8(a, b, c, 0, 0, 0)

#define EPSQ 1e-8f

// ---------------- Quant: one block per token (K == 4096 fast path) ----------------
__global__ __launch_bounds__(256) void quant4096(
    const float* __restrict__ x, int8_t* __restrict__ xq, float* __restrict__ sx)
{
    constexpr int K = 4096;
    const int t = blockIdx.x;
    const int tid = threadIdx.x;
    const float4* row4 = (const float4*)(x + (size_t)t * K);
    float4 v0 = row4[0 * 256 + tid];
    float4 v1 = row4[1 * 256 + tid];
    float4 v2 = row4[2 * 256 + tid];
    float4 v3 = row4[3 * 256 + tid];
    auto mx4 = [](float4 a) {
        return fmaxf(fmaxf(fabsf(a.x), fabsf(a.y)), fmaxf(fabsf(a.z), fabsf(a.w)));
    };
    float am = fmaxf(fmaxf(mx4(v0), mx4(v1)), fmaxf(mx4(v2), mx4(v3)));
    #pragma unroll
    for (int off = 32; off > 0; off >>= 1)
        am = fmaxf(am, __shfl_xor(am, off, 64));
    __shared__ float wmax[4];
    if ((tid & 63) == 0) wmax[tid >> 6] = am;
    __syncthreads();
    float r = fmaxf(fmaxf(wmax[0], wmax[1]), fmaxf(wmax[2], wmax[3]));
    const float s = fmaxf(r, EPSQ) / 127.0f;   // true fdiv: match reference
    if (tid == 0) sx[t] = s;
    int* qrow = (int*)(xq + (size_t)t * K);
    auto pack = [&](float4 a) {
        int q0 = (int)fminf(fmaxf(rintf(a.x / s), -128.f), 127.f);
        int q1 = (int)fminf(fmaxf(rintf(a.y / s), -128.f), 127.f);
        int q2 = (int)fminf(fmaxf(rintf(a.z / s), -128.f), 127.f);
        int q3 = (int)fminf(fmaxf(rintf(a.w / s), -128.f), 127.f);
        return (q0 & 255) | ((q1 & 255) << 8) | ((q2 & 255) << 16) | ((q3 & 255) << 24);
    };
    qrow[0 * 256 + tid] = pack(v0);
    qrow[1 * 256 + tid] = pack(v1);
    qrow[2 * 256 + tid] = pack(v2);
    qrow[3 * 256 + tid] = pack(v3);
}

// generic fallback (any K multiple of 4)
__global__ __launch_bounds__(256) void quant_any(
    const float* __restrict__ x, int8_t* __restrict__ xq, float* __restrict__ sx, int K)
{
    const int t = blockIdx.x;
    const int tid = threadIdx.x;
    const float* row = x + (size_t)t * K;
    float am = 0.f;
    for (int i = tid; i < K; i += 256) am = fmaxf(am, fabsf(row[i]));
    #pragma unroll
    for (int off = 32; off > 0; off >>= 1)
        am = fmaxf(am, __shfl_xor(am, off, 64));
    __shared__ float wmax[4];
    if ((tid & 63) == 0) wmax[tid >> 6] = am;
    __syncthreads();
    float r = fmaxf(fmaxf(wmax[0], wmax[1]), fmaxf(wmax[2], wmax[3]));
    const float s = fmaxf(r, EPSQ) / 127.0f;
    if (tid == 0) sx[t] = s;
    int8_t* qrow = xq + (size_t)t * K;
    for (int i = tid; i < K; i += 256) {
        float q = fminf(fmaxf(rintf(row[i] / s), -128.f), 127.f);
        qrow[i] = (int8_t)(int)q;
    }
}

// ---------------- Pack: weight arrives as int32 (harness ABI), repack to int8 ----------------
__global__ __launch_bounds__(256) void pack_w(
    const int* __restrict__ w32, int8_t* __restrict__ w8, long long n4)
{
    const long long stride = (long long)gridDim.x * 256;
    for (long long i = (long long)blockIdx.x * 256 + threadIdx.x; i < n4; i += stride) {
        int4 v = ((const int4*)w32)[i];
        ((int*)w8)[i] = (v.x & 255) | ((v.y & 255) << 8) | ((v.z & 255) << 16) | ((v.w & 255) << 24);
    }
}

// ---------------- int8 GEMM: branchless sched-walled group interleave ----------------
// BM=256, BN=192, BK=128 (full tile). 512 thr, 8 waves (2M x 4N), wave tile
// 128x48 = 8x3 frags 16x16x64, two 64B K-halves per tile -> 48 MFMA + 22
// ds_read_b128 + 7 gload16 per tile per wave-equivalent.
// THE FIX vs R10/R11 (VGPR=112 proved reads were sunk to their MFMA use):
// steady-state tile body is STRAIGHT-LINE (no branches) with sched_barrier(0)
// walls between groups: reads issue ahead, compiler inserts its own counted
// lgkmcnt(8/4/0) between groups (m97-verified), MFMA groups run while later
// read-groups' data is still in flight -> LDS pipe overlaps matrix pipe.
// LDS: 2 bufs x 56KB (A 32KB | B 24KB) = 112KB -> 1 block/CU, 2 waves/SIMD.
// One vmcnt(0)+barrier per tile: stage(t+1) issued a FULL tile (~2000cyc >>
// 900cyc HBM) before its wait -> drain costs ~nothing (unlike R2's 400cyc gap).
// Buffer safety: stage(t+1) writes buf[t^1], whose readers (tile t-1) all
// passed the top-of-tile-t barrier.
// Swizzle: R2-counter-verified (SQ_LDS_BANK_CONFLICT==0) two-64B-logical-rows-
// per-128B-phys-row XOR x^=(R&7)<<4; linear gload_lds dest + inverse-swizzled
// per-lane global src (rule #21).
// Grid (M/256)*(N/192) = 16*32 = 512 = exactly 2 rounds/CU, zero tail waste.
__global__ __launch_bounds__(512, 2) void gemm_i8(
    const int8_t* __restrict__ xq, const int8_t* __restrict__ w,
    const float* __restrict__ sx, const float* __restrict__ scale,
    const float* __restrict__ bias, float* __restrict__ out,
    int M, int N, int K)
{
    __shared__ __align__(16) uint8_t lds[2][57344];   // [buf][A 32KB | B 24KB]
    const int tid  = threadIdx.x;
    const int lane = tid & 63;
    const int wv   = tid >> 6;
    const int wr   = wv >> 2, wc = wv & 3;

    // bijective XCD swizzle (m204); nwg=512 -> %8==0
    const int nwg = gridDim.x;
    const int q8 = nwg >> 3, r8 = nwg & 7;
    const int xcd = blockIdx.x & 7, idx8 = blockIdx.x >> 3;
    const int wg = (xcd < r8 ? xcd * (q8 + 1) : r8 * (q8 + 1) + (xcd - r8) * q8) + idx8;

    const int NBM = M >> 8;
    const int bm = wg % NBM;
    const int bn = wg / NBM;             // col-panel-major: B panel (768KB) L2-resident
    const int brow = bm << 8, bcol = bn * 192;

    // staging sources (inverse-swizzled; R2-verified formula).
    // A region: [half][128 phys rows][128B] x2 halves = 32KB; chunk li=(e&1)*512+tid.
    const int8_t* srcA[4];
    #pragma unroll
    for (int e = 0; e < 4; ++e) {
        int half = e >> 1;
        int li = (e & 1) * 512 + tid;
        int R  = li >> 3;
        int xx = ((li & 7) << 4) ^ ((R & 7) << 4);
        srcA[e] = xq + (size_t)(brow + ((R << 1) | (xx >> 6))) * K + half * 64 + (xx & 63);
    }
    // B region: [half][96 phys rows][128B] x2 = 24KB contiguous; chunk li=e*512+tid.
    const int8_t* srcB[3];
    #pragma unroll
    for (int e = 0; e < 3; ++e) {
        int li = e * 512 + tid;
        int halfB = (li >= 768) ? 1 : 0;
        int lw = li - halfB * 768;
        int R  = lw >> 3;
        int xx = ((li & 7) << 4) ^ ((R & 7) << 4);
        srcB[e] = w + (size_t)(bcol + ((R << 1) | (xx >> 6))) * K + halfB * 64 + (xx & 63);
    }

    // fragment LDS byte offsets within a half-region (R2-verified formula)
    int offA[8], offB[3];
    #pragma unroll
    for (int m = 0; m < 8; ++m) {
        int r  = wr * 128 + m * 16 + (lane & 15);
        int R  = r >> 1;
        int x  = (((r & 1) << 6) | (lane & 48)) ^ ((R & 7) << 4);
        offA[m] = R * 128 + x;
    }
    #pragma unroll
    for (int n = 0; n < 3; ++n) {
        int r  = wc * 48 + n * 16 + (lane & 15);
        int R  = r >> 1;
        int x  = (((r & 1) << 6) | (lane & 48)) ^ ((R & 7) << 4);
        offB[n] = R * 128 + x;
    }

    i32x4 acc[8][3] = {};

#define STAGE(NB, TT) do { const size_t ko = (size_t)(TT) << 7;      \
        gload16(srcA[0] + ko, &lds[NB][        wv * 1024]);          \
        gload16(srcA[1] + ko, &lds[NB][ 8192 + wv * 1024]);          \
        gload16(srcA[2] + ko, &lds[NB][16384 + wv * 1024]);          \
        gload16(srcA[3] + ko, &lds[NB][24576 + wv * 1024]);          \
        gload16(srcB[0] + ko, &lds[NB][32768 + wv * 1024]);          \
        gload16(srcB[1] + ko, &lds[NB][40960 + wv * 1024]);          \
        gload16(srcB[2] + ko, &lds[NB][49152 + wv * 1024]); } while (0)

#define RA(BUF, HH, V, MM) V = *(const i32x4*)(&lds[BUF][(HH) * 16384 + offA[MM]])
#define RB(BUF, HH, V, NN) V = *(const i32x4*)(&lds[BUF][32768 + (HH) * 12288 + offB[NN]])

#define TILE(BUF, TT, DOSTAGE) do {                                           \
        i32x4 a0,a1,a2,a3,a4,a5,a6,a7,b0,b1,b2;                               \
        i32x4 c0,c1,c2,c3,c4,c5,c6,c7,d0,d1,d2;                               \
        VMCNT0(); BARRIER(); SB();                                            \
        RA(BUF,0,a0,0); RA(BUF,0,a1,1); RB(BUF,0,b0,0); RB(BUF,0,b1,1); SB(); \
        RA(BUF,0,a2,2); RA(BUF,0,a3,3); RB(BUF,0,b2,2); SB();                 \
        RA(BUF,0,a4,4); RA(BUF,0,a5,5); RA(BUF,0,a6,6); RA(BUF,0,a7,7); SB(); \
        if (DOSTAGE) { STAGE(BUF ^ 1, (TT) + 1); }                            \
        SB();                                                                 \
        SP1();                                                                \
        acc[0][0]=MFMAI8(a0,b0,acc[0][0]); acc[1][0]=MFMAI8(a1,b0,acc[1][0]); \
        acc[0][1]=MFMAI8(a0,b1,acc[0][1]); acc[1][1]=MFMAI8(a1,b1,acc[1][1]); \
        SP0(); SB();                                                          \
        RA(BUF,1,c0,0); RA(BUF,1,c1,1); RB(BUF,1,d0,0); RB(BUF,1,d1,1); SB(); \
        SP1();                                                                \
        acc[0][2]=MFMAI8(a0,b2,acc[0][2]); acc[1][2]=MFMAI8(a1,b2,acc[1][2]); \
        acc[2][0]=MFMAI8(a2,b0,acc[2][0]); acc[3][0]=MFMAI8(a3,b0,acc[3][0]); \
        acc[2][1]=MFMAI8(a2,b1,acc[2][1]); acc[3][1]=MFMAI8(a3,b1,acc[3][1]); \
        acc[2][2]=MFMAI8(a2,b2,acc[2][2]); acc[3][2]=MFMAI8(a3,b2,acc[3][2]); \
        SP0(); SB();                                                          \
        RA(BUF,1,c2,2); RA(BUF,1,c3,3); RB(BUF,1,d2,2); SB();                 \
        SP1();                                                                \
        acc[4][0]=MFMAI8(a4,b0,acc[4][0]); acc[5][0]=MFMAI8(a5,b0,acc[5][0]); \
        acc[6][0]=MFMAI8(a6,b0,acc[6][0]); acc[7][0]=MFMAI8(a7,b0,acc[7][0]); \
        acc[4][1]=MFMAI8(a4,b1,acc[4][1]); acc[5][1]=MFMAI8(a5,b1,acc[5][1]); \
        acc[6][1]=MFMAI8(a6,b1,acc[6][1]); acc[7][1]=MFMAI8(a7,b1,acc[7][1]); \
        acc[4][2]=MFMAI8(a4,b2,acc[4][2]); acc[5][2]=MFMAI8(a5,b2,acc[5][2]); \
        acc[6][2]=MFMAI8(a6,b2,acc[6][2]); acc[7][2]=MFMAI8(a7,b2,acc[7][2]); \
        SP0(); SB();                                                          \
        RA(BUF,1,c4,4); RA(BUF,1,c5,5); RA(BUF,1,c6,6); RA(BUF,1,c7,7); SB(); \
        SP1();                                                                \
        acc[0][0]=MFMAI8(c0,d0,acc[0][0]); acc[1][0]=MFMAI8(c1,d0,acc[1][0]); \
        acc[0][1]=MFMAI8(c0,d1,acc[0][1]); acc[1][1]=MFMAI8(c1,d1,acc[1][1]); \
        acc[0][2]=MFMAI8(c0,d2,acc[0][2]); acc[1][2]=MFMAI8(c1,d2,acc[1][2]); \
        acc[2][0]=MFMAI8(c2,d0,acc[2][0]); acc[3][0]=MFMAI8(c3,d0,acc[3][0]); \
        acc[2][1]=MFMAI8(c2,d1,acc[2][1]); acc[3][1]=MFMAI8(c3,d1,acc[3][1]); \
        acc[2][2]=MFMAI8(c2,d2,acc[2][2]); acc[3][2]=MFMAI8(c3,d2,acc[3][2]); \
        acc[4][0]=MFMAI8(c4,d0,acc[4][0]); acc[5][0]=MFMAI8(c5,d0,acc[5][0]); \
        acc[6][0]=MFMAI8(c6,d0,acc[6][0]); acc[7][0]=MFMAI8(c7,d0,acc[7][0]); \
        acc[4][1]=MFMAI8(c4,d1,acc[4][1]); acc[5][1]=MFMAI8(c5,d1,acc[5][1]); \
        acc[6][1]=MFMAI8(c6,d1,acc[6][1]); acc[7][1]=MFMAI8(c7,d1,acc[7][1]); \
        acc[4][2]=MFMAI8(c4,d2,acc[4][2]); acc[5][2]=MFMAI8(c5,d2,acc[5][2]); \
        acc[6][2]=MFMAI8(c6,d2,acc[6][2]); acc[7][2]=MFMAI8(c7,d2,acc[7][2]); \
        SP0(); SB();                                                          \
    } while (0)

    const int NT = K >> 7;               // 32 for K=4096 (even)
    STAGE(0, 0);
    for (int t = 0; t < NT - 2; t += 2) {
        TILE(0, t,     true);
        TILE(1, t + 1, true);
    }
    TILE(0, NT - 2, true);               // stages tile NT-1 into buf 1
    TILE(1, NT - 1, false);

    // epilogue: out = acc * sx[row] * scale[col] + bias[col]
    const int orow = brow + wr * 128;
    const int ocol = bcol + wc * 48;
    float sxv[8][4];
    #pragma unroll
    for (int m = 0; m < 8; ++m)
        #pragma unroll
        for (int j = 0; j < 4; ++j)
            sxv[m][j] = sx[orow + m * 16 + ((lane >> 4) << 2) + j];
    #pragma unroll
    for (int n = 0; n < 3; ++n) {
        const int col = ocol + n * 16 + (lane & 15);
        const float sc = scale[col];
        const float bi = bias[col];
        #pragma unroll
        for (int m = 0; m < 8; ++m) {
            const int rb = orow + m * 16 + ((lane >> 4) << 2);
            #pragma unroll
            for (int j = 0; j < 4; ++j)
                out[(size_t)(rb + j) * N + col] = (float)acc[m][n][j] * sxv[m][j] * sc + bi;
        }
    }
}

extern "C" void kernel_launch(void* const* d_in, const int* in_sizes, int n_in,
                              void* d_out, int out_size, void* d_ws, size_t ws_size,
                              hipStream_t stream) {
    const float* x     = (const float*)d_in[0];
    const int*   w32   = (const int*)d_in[1];     // int8 weight arrives as int32 (harness ABI)
    const float* scale = (const float*)d_in[2];
    const float* bias  = (const float*)d_in[3];
    float* out = (float*)d_out;

    const int N = in_sizes[2];           // 6144
    const int K = in_sizes[1] / N;       // 4096
    const int M = in_sizes[0] / K;       // 4096

    // ws layout: xq [M*K int8] | wq [N*K int8] | sx [M f32]
    int8_t* xqbuf = (int8_t*)d_ws;
    int8_t* wqbuf = (int8_t*)d_ws + (size_t)M * K;
    float*  sxbuf = (float*)((uint8_t*)d_ws + (size_t)M * K + (size_t)N * K);

    if (K == 4096)
        quant4096<<<M, 256, 0, stream>>>(x, xqbuf, sxbuf);
    else
        quant_any<<<M, 256, 0, stream>>>(x, xqbuf, sxbuf, K);

    pack_w<<<2048, 256, 0, stream>>>(w32, wqbuf, (long long)N * K / 4);

    const int nwg = (M / 256) * (N / 192);   // 16*32 = 512
    gemm_i8<<<nwg, 512, 0, stream>>>(xqbuf, wqbuf, sxbuf, scale, bias, out, M, N, K);
}